// Round 1
// 465.865 us; speedup vs baseline: 1.0088x; 1.0088x over previous
//
#include <hip/hip_runtime.h>
#include <math.h>

#define N_TOKENS 32768
#define EMBED    2048
#define NEXP     64
#define TOPK     8
#define BM       64
#define BK       64
#define NCH      (EMBED / BK)     // 32
#define SCS      65
#define THRESH   1e-4f
#define WELEMS   (NEXP * EMBED)
#define FIXGRID  1024

typedef __attribute__((ext_vector_type(8)))  short short8;
typedef __attribute__((ext_vector_type(16))) float f32x16;
typedef __attribute__((ext_vector_type(4)))  unsigned int uint4v;

// one-instruction packed fp32->bf16 RNE (gfx950), D[15:0]=bf16(a), D[31:16]=bf16(b)
__device__ __forceinline__ unsigned pkbf(float a, float b) {
  unsigned r;
  asm("v_cvt_pk_bf16_f32 %0, %1, %2" : "=v"(r) : "v"(a), "v"(b));
  return r;
}

// 8 fp32 -> bf16 hi (RNE) + bf16 lo (RNE of exact residual), packed directly in
// MFMA-operand order. Numerically identical to the old bf16rne bit-trick path.
__device__ __forceinline__ void cvt8(float4 fa, float4 fb, short8* h8, short8* l8) {
  const unsigned h0 = pkbf(fa.x, fa.y), h1 = pkbf(fa.z, fa.w);
  const unsigned h2 = pkbf(fb.x, fb.y), h3 = pkbf(fb.z, fb.w);
  const float l0 = fa.x - __uint_as_float(h0 << 16);
  const float l1 = fa.y - __uint_as_float(h0 & 0xFFFF0000u);
  const float l2 = fa.z - __uint_as_float(h1 << 16);
  const float l3 = fa.w - __uint_as_float(h1 & 0xFFFF0000u);
  const float l4 = fb.x - __uint_as_float(h2 << 16);
  const float l5 = fb.y - __uint_as_float(h2 & 0xFFFF0000u);
  const float l6 = fb.z - __uint_as_float(h3 << 16);
  const float l7 = fb.w - __uint_as_float(h3 & 0xFFFF0000u);
  const uint4v H = {h0, h1, h2, h3};
  const uint4v L = {pkbf(l0, l1), pkbf(l2, l3), pkbf(l4, l5), pkbf(l6, l7)};
  *h8 = __builtin_bit_cast(short8, H);
  *l8 = __builtin_bit_cast(short8, L);
}

// W [64,2048] fp32 -> bf16 hi/lo in MFMA B-fragment layout. Also zeroes gcnt
// (d_ws is re-poisoned each launch; router's atomics need it zeroed first).
__global__ void split_w(const float* __restrict__ W, short* __restrict__ wh,
                        short* __restrict__ wl, int* __restrict__ gcnt) {
  if (blockIdx.x == 0 && threadIdx.x == 0) *gcnt = 0;
  const int T = blockIdx.x * 256 + threadIdx.x;   // 0..16383
  const int n = T >> 8, kg8 = T & 255;
  const float4* W4 = (const float4*)W;
  float4 a = W4[n * 512 + kg8 * 2];
  float4 b = W4[n * 512 + kg8 * 2 + 1];
  short8 h, l;
  cvt8(a, b, &h, &l);
  *(short8*)&wh[(kg8 * 64 + n) * 8] = h;
  *(short8*)&wl[(kg8 * 64 + n) * 8] = l;
}

__global__ __launch_bounds__(256, 2)
void router_kernel(const float* __restrict__ x, const short* __restrict__ wh,
                   const short* __restrict__ wl, const float* __restrict__ bias,
                   int* __restrict__ gcnt, int* __restrict__ glist,
                   float* __restrict__ out) {
  // x staged RAW fp32 via global_load_lds, TRIPLE-buffered (2-deep prefetch),
  // XOR-swizzled. Counted vmcnt + raw s_barrier: never drain the load queue
  // in the main loop (T3/T4).
  __shared__ float4 lx[3][1024];     // 48 KB
  float* sc = (float*)&lx[0][0];     // overlay: used only after the K-loop

  const int tid  = threadIdx.x;
  const int t0   = blockIdx.x * BM;
  const int lane = tid & 63;
  const int w    = tid >> 6;
  const int half = lane >> 5;
  const int r5   = lane & 31;
  const int tw   = (w & 1) * 32;
  const int ew   = (w >> 1) * 32;

  const float4* x4g = (const float4*)x;
  const short8* Bh  = (const short8*)wh;
  const short8* Bl  = (const short8*)wl;
  const int boff = half * 64 + ew + r5;

  const int row16 = tid >> 4;
  const int s4    = tid & 15;
  const int c4sw  = s4 ^ row16;
  const int wbase = (tid & 192);

  const float4* gbase = x4g + (size_t)(t0 + row16) * (EMBED / 4) + c4sw;

  // prologue: prefetch chunk 0 -> buf0, chunk 1 -> buf1 (8 loads in flight)
#pragma unroll
  for (int i = 0; i < 4; ++i)
    __builtin_amdgcn_global_load_lds((const void*)(gbase + (size_t)16 * i * (EMBED / 4)),
                                     (void*)&lx[0][i * 256 + wbase], 16, 0, 0);
#pragma unroll
  for (int i = 0; i < 4; ++i)
    __builtin_amdgcn_global_load_lds((const void*)(gbase + (size_t)16 * i * (EMBED / 4) + 16),
                                     (void*)&lx[1][i * 256 + wbase], 16, 0, 0);

  const int arow  = tw + r5;
  const int am    = arow & 15;
  const int abase = (arow >> 4) * 256 + am * 16;

  f32x16 acc;
#pragma unroll
  for (int i = 0; i < 16; ++i) acc[i] = 0.f;

  int bc = 0, bp = 2;
  for (int ch = 0; ch < NCH; ++ch) {
    // need chunk ch landed: <=4 outstanding leaves only the newest prefetch
    // batch (ch+1) in flight. Final chunk drains fully.
    if (ch + 1 < NCH) asm volatile("s_waitcnt vmcnt(4)" ::: "memory");
    else              asm volatile("s_waitcnt vmcnt(0)" ::: "memory");
    __builtin_amdgcn_s_barrier();
    __builtin_amdgcn_sched_barrier(0);

    // B fragments FIRST (older than the prefetch in vmcnt FIFO), so the
    // compiler's wait before MFMA is vmcnt(4), not vmcnt(0).
    short8 bh[4], bl[4];
#pragma unroll
    for (int s = 0; s < 4; ++s) {
      const int bi = (ch * 4 + s) * 128 + boff;
      bh[s] = Bh[bi]; bl[s] = Bl[bi];
    }
    __builtin_amdgcn_sched_barrier(0);

    if (ch + 2 < NCH) {
#pragma unroll
      for (int i = 0; i < 4; ++i)
        __builtin_amdgcn_global_load_lds(
            (const void*)(gbase + (size_t)16 * i * (EMBED / 4) + (ch + 2) * 16),
            (void*)&lx[bp][i * 256 + wbase], 16, 0, 0);
    }

#pragma unroll
    for (int s = 0; s < 4; ++s) {
      const int c0 = s * 4 + half * 2;
      float4 fa = lx[bc][abase + (c0 ^ am)];
      float4 fb = lx[bc][abase + ((c0 + 1) ^ am)];
      short8 ah, al;
      cvt8(fa, fb, &ah, &al);
      acc = __builtin_amdgcn_mfma_f32_32x32x16_bf16(ah, bh[s], acc, 0, 0, 0);
      acc = __builtin_amdgcn_mfma_f32_32x32x16_bf16(ah, bl[s], acc, 0, 0, 0);
      acc = __builtin_amdgcn_mfma_f32_32x32x16_bf16(al, bh[s], acc, 0, 0, 0);
    }
    bc = (bc == 2) ? 0 : bc + 1;
    bp = (bp == 2) ? 0 : bp + 1;
  }

  __syncthreads();

  // C layout (32x32): col = lane&31, row = (reg&3) + 8*(reg>>2) + 4*(lane>>5)
#pragma unroll
  for (int reg = 0; reg < 16; ++reg) {
    const int row = (reg & 3) + 8 * (reg >> 2) + 4 * half;
    sc[(tw + row) * SCS + ew + r5] = acc[reg];
  }
  __syncthreads();

  float* rout = out;
  float* iout = out + (size_t)N_TOKENS * NEXP;
  const float bias_l = bias[lane];

  for (int tb = 0; tb < 4; ++tb) {
    const int tbase = w * 16 + tb * 4;
    float orig[4]; unsigned cur[4];
#pragma unroll
    for (int i = 0; i < 4; ++i) {
      orig[i] = sc[(tbase + i) * SCS + lane] + bias_l;
      unsigned b = __float_as_uint(orig[i]);
      unsigned u = b ^ (((unsigned)((int)b >> 31)) | 0x80000000u);
      cur[i] = (u & 0xFFFFFFC0u) | (63u - (unsigned)lane);
    }
    float m[4], Z[4], ming[4], prev[4], morig[4];
    int myidx[4]; bool sel[4];
#pragma unroll
    for (int i = 0; i < 4; ++i) { sel[i] = false; morig[i] = 0.f; myidx[i] = 0; ming[i] = 1e30f; }

#pragma unroll
    for (int r = 0; r < 9; ++r) {
      unsigned v[4];
#pragma unroll
      for (int i = 0; i < 4; ++i) v[i] = cur[i];
#pragma unroll
      for (int s2 = 1; s2 < 64; s2 <<= 1) {
#pragma unroll
        for (int i = 0; i < 4; ++i) {
          unsigned o = (unsigned)__shfl_xor((int)v[i], s2);
          v[i] = v[i] > o ? v[i] : o;
        }
      }
#pragma unroll
      for (int i = 0; i < 4; ++i) {
        unsigned vb = (v[i] & 0x80000000u) ? (v[i] ^ 0x80000000u) : ~v[i];
        float fv = __uint_as_float(vb);
        if (r == 0) { m[i] = fmaxf(fv, 0.f); Z[i] = 56.f * expf(-m[i]) + expf(fv - m[i]); }
        else {
          ming[i] = fminf(ming[i], prev[i] - fv);
          if (r < 8) Z[i] += expf(fv - m[i]);
        }
        prev[i] = fv;
        if (r < 8) {
          if (lane == r) myidx[i] = 63 - (int)(v[i] & 63u);
          if (cur[i] == v[i]) { sel[i] = true; morig[i] = orig[i]; cur[i] = 0u; }
        }
      }
    }
#pragma unroll
    for (int i = 0; i < 4; ++i) {
      const int t = tbase + i;
      if (ming[i] < THRESH) {
        if (lane == 0) { int p = atomicAdd(gcnt, 1); glist[p] = t0 + t; }
      } else {
        const float p = expf(morig[i] - m[i]) / Z[i];
        rout[(size_t)(t0 + t) * NEXP + lane] = p;
        if (lane < TOPK) iout[(size_t)(t0 + t) * TOPK + lane] = (float)myidx[i];
      }
    }
  }
}

// Exact fp64 recompute for ambiguous tokens; one token per block-iteration.
__global__ __launch_bounds__(256, 4)
void fixup_kernel(const float* __restrict__ x, const float* __restrict__ Wf,
                  const float* __restrict__ bias, const int* __restrict__ gcnt,
                  const int* __restrict__ glist, float* __restrict__ out) {
  __shared__ float4 xsh[512];        // 8 KB x row
  __shared__ double sco[NEXP];
  const int tid  = threadIdx.x;
  const int lane = tid & 63;
  const int w    = tid >> 6;
  float* rout = out;
  float* iout = out + (size_t)N_TOKENS * NEXP;
  const int cnt = *gcnt;

  for (int j = blockIdx.x; j < cnt; j += FIXGRID) {
    const int tok = glist[j];
    const float4* xr = (const float4*)x + (size_t)tok * 512;
    xsh[tid] = xr[tid];
    xsh[tid + 256] = xr[tid + 256];
    __syncthreads();

    // wave w handles experts 16w..16w+15, lanes fully coalesced over k
    for (int i = 0; i < 16; ++i) {
      const int e = w * 16 + i;
      const float4* wr = (const float4*)Wf + (size_t)e * 512;
      double a = 0.0;
#pragma unroll
      for (int q = 0; q < 8; ++q) {
        float4 wv = wr[q * 64 + lane];     // contiguous 1 KB per instruction
        float4 xv = xsh[q * 64 + lane];
        a = fma((double)xv.x, (double)wv.x, a);
        a = fma((double)xv.y, (double)wv.y, a);
        a = fma((double)xv.z, (double)wv.z, a);
        a = fma((double)xv.w, (double)wv.w, a);
      }
#pragma unroll
      for (int s2 = 1; s2 < 64; s2 <<= 1) a += __shfl_xor(a, s2);
      if (lane == 0) sco[e] = a + (double)bias[e];
    }
    __syncthreads();

    if (w == 0) {                      // exact fp64 top-8 (R2-proven)
      const double orig = sco[lane];
      double curd = orig, vals[8];
      int myidx = 0; double mym = 0.0;
#pragma unroll
      for (int r = 0; r < 8; ++r) {
        double v = curd; int id = lane;
#pragma unroll
        for (int s2 = 1; s2 < 64; s2 <<= 1) {
          const double ov = __shfl_xor(v, s2);
          const int    oi = __shfl_xor(id, s2);
          if (ov > v || (ov == v && oi < id)) { v = ov; id = oi; }
        }
        vals[r] = v;
        if (lane == r)  myidx = id;
        if (lane == id) { mym = orig; curd = -1e300; }
      }
      const double md = fmax(vals[0], 0.0);
      double Zd = 56.0 * exp(-md);
#pragma unroll
      for (int r = 0; r < 8; ++r) Zd += exp(vals[r] - md);
      const double p = exp(mym - md) / Zd;
      rout[(size_t)tok * NEXP + lane] = (float)p;
      if (lane < TOPK) iout[(size_t)tok * TOPK + lane] = (float)myidx;
    }
    __syncthreads();
  }
}

extern "C" void kernel_launch(void* const* d_in, const int* in_sizes, int n_in,
                              void* d_out, int out_size, void* d_ws, size_t ws_size,
                              hipStream_t stream) {
  const float* x = (const float*)d_in[0];
  const float* W = (const float*)d_in[1];
  const float* b = (const float*)d_in[2];
  short* wh = (short*)d_ws;
  short* wl = wh + WELEMS;
  int* gcnt  = (int*)(wl + WELEMS);      // 1 MB offset, 4-aligned
  int* glist = gcnt + 4;                 // capacity 32768 ints

  split_w<<<64, 256, 0, stream>>>(W, wh, wl, gcnt);
  router_kernel<<<N_TOKENS / BM, 256, 0, stream>>>(x, wh, wl, b, gcnt, glist,
                                                   (float*)d_out);
  fixup_kernel<<<FIXGRID, 256, 0, stream>>>(x, W, b, gcnt, glist, (float*)d_out);
}